// Round 1
// baseline (237.445 us; speedup 1.0000x reference)
//
#include <hip/hip_runtime.h>
#include <math.h>

#define S_SIMS 4096
#define T_LEN  500
#define D_DIM  6
#define A_DIM  3
#define H_DIM  64
#define ALPHA_C 0.1f

// ---------------------------------------------------------------------------
// Main kernel: one wave (64 lanes) per simulation s. Lane i handles
// t = i, i+64, ... (coalesced: T is the contiguous axis of [S,D,T]).
// Per (t,s): policy MLP (6->64->3) and baseline MLP (6->64->1), fused so the
// hidden unit h[j] is consumed immediately (3+1 fmas) -- no h[] array.
// Accumulate SL[s] = sum_t ll, AS[s] = sum_t ((t+1)*g - baseline).
// ---------------------------------------------------------------------------
__global__ __launch_bounds__(256) void mepg_main(
    const float* __restrict__ state,   // [S, D, T]
    const float* __restrict__ action,  // [S, A, T]
    const float* __restrict__ reward,  // [S, T]
    const float* __restrict__ pW1,     // [H, D]
    const float* __restrict__ pb1,     // [H]
    const float* __restrict__ pW2,     // [A, H]
    const float* __restrict__ pb2,     // [A]
    const float* __restrict__ bW1,     // [H, D]
    const float* __restrict__ bb1,     // [H]
    const float* __restrict__ bW2,     // [1, H]
    const float* __restrict__ bb2,     // [1]
    const float* __restrict__ sd,      // [A, A]
    float* __restrict__ ASa,           // [S] out
    float* __restrict__ SLa)           // [S] out
{
    // ---- stage packed weights in LDS: 20 floats per hidden unit j ----------
    // k: 0..5 pW1[j][0..5] | 6 pb1[j] | 7..9 pW2[0..2][j] | 10 bb1[j]
    //    11 bW2[j] | 12..17 bW1[j][0..5] | 18..19 pad
    __shared__ float wpack[H_DIM * 20];
    const int tid = threadIdx.x;
    if (tid < H_DIM) {
        const int j = tid;
        float* w = &wpack[j * 20];
#pragma unroll
        for (int d = 0; d < D_DIM; ++d) w[d] = pW1[j * D_DIM + d];
        w[6]  = pb1[j];
        w[7]  = pW2[0 * H_DIM + j];
        w[8]  = pW2[1 * H_DIM + j];
        w[9]  = pW2[2 * H_DIM + j];
        w[10] = bb1[j];
        w[11] = bW2[j];
#pragma unroll
        for (int d = 0; d < D_DIM; ++d) w[12 + d] = bW1[j * D_DIM + d];
        w[18] = 0.f; w[19] = 0.f;
    }
    __syncthreads();

    // ---- sd^{-1} (3x3 symmetric) + log-det constant, uniform per thread ----
    const float s00 = sd[0], s01 = sd[1], s02 = sd[2];
    const float s11 = sd[4], s12 = sd[5], s22 = sd[8];
    const float det = s00 * (s11 * s22 - s12 * s12)
                    - s01 * (s01 * s22 - s12 * s02)
                    + s02 * (s01 * s12 - s11 * s02);
    const float idet = 1.0f / det;
    const float M00 = (s11 * s22 - s12 * s12) * idet;
    const float M01 = (s02 * s12 - s01 * s22) * idet;
    const float M02 = (s01 * s12 - s02 * s11) * idet;
    const float M11 = (s00 * s22 - s02 * s02) * idet;
    const float M12 = (s01 * s02 - s00 * s12) * idet;
    const float M22 = (s00 * s11 - s01 * s01) * idet;
    // ll = -0.5 * d^T M d + c0 ; c0 = -0.5*log(det) - 0.5*A*log(2*pi)
    const float c0 = -0.5f * logf(det) - 0.5f * (float)A_DIM * logf(6.2831853071795864769f);

    const float pb2_0 = pb2[0], pb2_1 = pb2[1], pb2_2 = pb2[2];
    const float bb2_0 = bb2[0];

    const int wave = tid >> 6;
    const int lane = tid & 63;
    const int s    = blockIdx.x * 4 + wave;

    const float* sbase = state  + (size_t)s * D_DIM * T_LEN;
    const float* abase = action + (size_t)s * A_DIM * T_LEN;
    const float* rbase = reward + (size_t)s * T_LEN;

    float SL = 0.f;
    float AS = 0.f;

    for (int t = lane; t < T_LEN; t += 64) {
        const float x0 = sbase[0 * T_LEN + t];
        const float x1 = sbase[1 * T_LEN + t];
        const float x2 = sbase[2 * T_LEN + t];
        const float x3 = sbase[3 * T_LEN + t];
        const float x4 = sbase[4 * T_LEN + t];
        const float x5 = sbase[5 * T_LEN + t];
        const float a0 = abase[0 * T_LEN + t];
        const float a1 = abase[1 * T_LEN + t];
        const float a2 = abase[2 * T_LEN + t];
        const float r  = rbase[t];

        float mu0 = pb2_0, mu1 = pb2_1, mu2 = pb2_2;
        float bl  = bb2_0;

#pragma unroll 4
        for (int j = 0; j < H_DIM; ++j) {
            const float4* wp = reinterpret_cast<const float4*>(&wpack[j * 20]);
            const float4 w0 = wp[0];  // pW1[0..3]
            const float4 w1 = wp[1];  // pW1[4], pW1[5], pb1, pW2_0
            const float4 w2 = wp[2];  // pW2_1, pW2_2, bb1, bW2
            const float4 w3 = wp[3];  // bW1[0..3]
            const float4 w4 = wp[4];  // bW1[4], bW1[5], pad, pad

            float pre = fmaf(x0, w0.x, fmaf(x1, w0.y, fmaf(x2, w0.z,
                        fmaf(x3, w0.w, fmaf(x4, w1.x, fmaf(x5, w1.y, w1.z))))));
            const float h = fmaxf(pre, 0.f);
            mu0 = fmaf(h, w1.w, mu0);
            mu1 = fmaf(h, w2.x, mu1);
            mu2 = fmaf(h, w2.y, mu2);

            float preb = fmaf(x0, w3.x, fmaf(x1, w3.y, fmaf(x2, w3.z,
                         fmaf(x3, w3.w, fmaf(x4, w4.x, fmaf(x5, w4.y, w2.z))))));
            const float hb = fmaxf(preb, 0.f);
            bl = fmaf(hb, w2.w, bl);
        }

        const float d0 = a0 - mu0;
        const float d1 = a1 - mu1;
        const float d2 = a2 - mu2;
        const float q  = M00 * d0 * d0 + M11 * d1 * d1 + M22 * d2 * d2
                       + 2.f * (M01 * d0 * d1 + M02 * d0 * d2 + M12 * d1 * d2);
        const float ll = -0.5f * q + c0;
        const float g  = expf(r) - ALPHA_C * ll;

        SL += ll;
        AS += (float)(t + 1) * g - bl;
    }

    // ---- wave (64-lane) reduction ----
#pragma unroll
    for (int o = 32; o > 0; o >>= 1) {
        SL += __shfl_xor(SL, o, 64);
        AS += __shfl_xor(AS, o, 64);
    }
    if (lane == 0) {
        ASa[s] = AS;
        SLa[s] = SL;
    }
}

// ---------------------------------------------------------------------------
// Final dot product: out = sum_s AS[s]*SL[s] / (T*S), f64 accumulate.
// ---------------------------------------------------------------------------
__global__ __launch_bounds__(256) void mepg_reduce(
    const float* __restrict__ ASa, const float* __restrict__ SLa,
    float* __restrict__ out)
{
    __shared__ double sh[256];
    double acc = 0.0;
    for (int i = threadIdx.x; i < S_SIMS; i += 256)
        acc += (double)ASa[i] * (double)SLa[i];
    sh[threadIdx.x] = acc;
    __syncthreads();
#pragma unroll
    for (int o = 128; o > 0; o >>= 1) {
        if (threadIdx.x < o) sh[threadIdx.x] += sh[threadIdx.x + o];
        __syncthreads();
    }
    if (threadIdx.x == 0)
        out[0] = (float)(sh[0] / ((double)T_LEN * (double)S_SIMS));
}

extern "C" void kernel_launch(void* const* d_in, const int* in_sizes, int n_in,
                              void* d_out, int out_size, void* d_ws, size_t ws_size,
                              hipStream_t stream) {
    const float* state  = (const float*)d_in[0];
    const float* action = (const float*)d_in[1];
    const float* reward = (const float*)d_in[2];
    const float* pW1    = (const float*)d_in[3];
    const float* pb1    = (const float*)d_in[4];
    const float* pW2    = (const float*)d_in[5];
    const float* pb2    = (const float*)d_in[6];
    const float* bW1    = (const float*)d_in[7];
    const float* bb1    = (const float*)d_in[8];
    const float* bW2    = (const float*)d_in[9];
    const float* bb2    = (const float*)d_in[10];
    const float* sd     = (const float*)d_in[11];

    float* ASa = (float*)d_ws;
    float* SLa = ASa + S_SIMS;

    dim3 block(256);
    dim3 grid(S_SIMS / 4);  // 4 waves per block, one simulation per wave
    mepg_main<<<grid, block, 0, stream>>>(state, action, reward,
                                          pW1, pb1, pW2, pb2,
                                          bW1, bb1, bW2, bb2, sd,
                                          ASa, SLa);
    mepg_reduce<<<1, block, 0, stream>>>(ASa, SLa, (float*)d_out);
}

// Round 2
// 176.604 us; speedup vs baseline: 1.3445x; 1.3445x over previous
//
#include <hip/hip_runtime.h>
#include <math.h>

#define S_SIMS 4096
#define T_LEN  500
#define D_DIM  6
#define A_DIM  3
#define H_DIM  64
#define ALPHA_C 0.1f
#define NT 8   // t-points per lane: ceil(500/64)

// ---------------------------------------------------------------------------
// One wave per simulation. Lane i owns t = i, i+64, ..., held in registers.
// Single pass over hidden units j: each 20-float weight pack is read from LDS
// ONCE per wave and applied to all NT=8 t-points (8x fewer LDS reads than the
// t-outer formulation, which was LDS-pipe-bound at 143us).
// ---------------------------------------------------------------------------
__global__ __launch_bounds__(256, 4) void mepg_main(
    const float* __restrict__ state,   // [S, D, T]
    const float* __restrict__ action,  // [S, A, T]
    const float* __restrict__ reward,  // [S, T]
    const float* __restrict__ pW1, const float* __restrict__ pb1,
    const float* __restrict__ pW2, const float* __restrict__ pb2,
    const float* __restrict__ bW1, const float* __restrict__ bb1,
    const float* __restrict__ bW2, const float* __restrict__ bb2,
    const float* __restrict__ sd,      // [A, A]
    float* __restrict__ ASa,           // [S] out
    float* __restrict__ SLa)           // [S] out
{
    // ---- packed weights in LDS: 20 floats per hidden unit j ----------------
    // 0..5 pW1[j][:] | 6 pb1[j] | 7..9 pW2[:][j] | 10 bb1[j] | 11 bW2[j]
    // 12..17 bW1[j][:] | 18..19 pad
    __shared__ float wpack[H_DIM * 20];
    const int tid = threadIdx.x;
    if (tid < H_DIM) {
        const int j = tid;
        float* w = &wpack[j * 20];
#pragma unroll
        for (int d = 0; d < D_DIM; ++d) w[d] = pW1[j * D_DIM + d];
        w[6]  = pb1[j];
        w[7]  = pW2[0 * H_DIM + j];
        w[8]  = pW2[1 * H_DIM + j];
        w[9]  = pW2[2 * H_DIM + j];
        w[10] = bb1[j];
        w[11] = bW2[j];
#pragma unroll
        for (int d = 0; d < D_DIM; ++d) w[12 + d] = bW1[j * D_DIM + d];
        w[18] = 0.f; w[19] = 0.f;
    }
    __syncthreads();

    // ---- sd^{-1} (3x3 symmetric) + log-det constant ------------------------
    const float s00 = sd[0], s01 = sd[1], s02 = sd[2];
    const float s11 = sd[4], s12 = sd[5], s22 = sd[8];
    const float det = s00 * (s11 * s22 - s12 * s12)
                    - s01 * (s01 * s22 - s12 * s02)
                    + s02 * (s01 * s12 - s11 * s02);
    const float idet = 1.0f / det;
    const float M00 = (s11 * s22 - s12 * s12) * idet;
    const float M01 = (s02 * s12 - s01 * s22) * idet;
    const float M02 = (s01 * s12 - s02 * s11) * idet;
    const float M11 = (s00 * s22 - s02 * s02) * idet;
    const float M12 = (s01 * s02 - s00 * s12) * idet;
    const float M22 = (s00 * s11 - s01 * s01) * idet;
    const float c0 = -0.5f * logf(det) - 0.5f * (float)A_DIM * logf(6.2831853071795864769f);

    const float pb2_0 = pb2[0], pb2_1 = pb2[1], pb2_2 = pb2[2];
    const float bb2_0 = bb2[0];

    const int wave = tid >> 6;
    const int lane = tid & 63;
    const int s    = blockIdx.x * 4 + wave;

    const float* sbase = state  + (size_t)s * D_DIM * T_LEN;
    const float* abase = action + (size_t)s * A_DIM * T_LEN;
    const float* rbase = reward + (size_t)s * T_LEN;

    // ---- load this lane's NT state points into registers -------------------
    float x[D_DIM][NT];
#pragma unroll
    for (int k = 0; k < NT; ++k) {
        const int t = lane + 64 * k;
        const bool v = (t < T_LEN);
        const int tc = v ? t : 0;
#pragma unroll
        for (int d = 0; d < D_DIM; ++d)
            x[d][k] = v ? sbase[d * T_LEN + tc] : 0.f;
    }

    float mu0[NT], mu1[NT], mu2[NT], bl[NT];
#pragma unroll
    for (int k = 0; k < NT; ++k) {
        mu0[k] = pb2_0; mu1[k] = pb2_1; mu2[k] = pb2_2; bl[k] = bb2_0;
    }

    // ---- single pass over hidden units: weights read once, applied to 8 t --
#pragma unroll 2
    for (int j = 0; j < H_DIM; ++j) {
        const float4* wp = reinterpret_cast<const float4*>(&wpack[j * 20]);
        const float4 w0 = wp[0];  // pW1[0..3]
        const float4 w1 = wp[1];  // pW1[4], pW1[5], pb1, pW2_0
        const float4 w2 = wp[2];  // pW2_1, pW2_2, bb1, bW2
        const float4 w3 = wp[3];  // bW1[0..3]
        const float4 w4 = wp[4];  // bW1[4], bW1[5], pad, pad
#pragma unroll
        for (int k = 0; k < NT; ++k) {
            const float pre = fmaf(x[0][k], w0.x, fmaf(x[1][k], w0.y, fmaf(x[2][k], w0.z,
                              fmaf(x[3][k], w0.w, fmaf(x[4][k], w1.x, fmaf(x[5][k], w1.y, w1.z))))));
            const float h = fmaxf(pre, 0.f);
            mu0[k] = fmaf(h, w1.w, mu0[k]);
            mu1[k] = fmaf(h, w2.x, mu1[k]);
            mu2[k] = fmaf(h, w2.y, mu2[k]);
            const float preb = fmaf(x[0][k], w3.x, fmaf(x[1][k], w3.y, fmaf(x[2][k], w3.z,
                               fmaf(x[3][k], w3.w, fmaf(x[4][k], w4.x, fmaf(x[5][k], w4.y, w2.z))))));
            const float hb = fmaxf(preb, 0.f);
            bl[k] = fmaf(hb, w2.w, bl[k]);
        }
    }

    // ---- epilogue: residual, loglik, advantage -----------------------------
    float SL = 0.f;
    float AS = 0.f;
#pragma unroll
    for (int k = 0; k < NT; ++k) {
        const int t = lane + 64 * k;
        if (t < T_LEN) {
            const float a0 = abase[0 * T_LEN + t];
            const float a1 = abase[1 * T_LEN + t];
            const float a2 = abase[2 * T_LEN + t];
            const float r  = rbase[t];
            const float d0 = a0 - mu0[k];
            const float d1 = a1 - mu1[k];
            const float d2 = a2 - mu2[k];
            const float q  = M00 * d0 * d0 + M11 * d1 * d1 + M22 * d2 * d2
                           + 2.f * (M01 * d0 * d1 + M02 * d0 * d2 + M12 * d1 * d2);
            const float ll = -0.5f * q + c0;
            const float g  = expf(r) - ALPHA_C * ll;
            SL += ll;
            AS += (float)(t + 1) * g - bl[k];
        }
    }

#pragma unroll
    for (int o = 32; o > 0; o >>= 1) {
        SL += __shfl_xor(SL, o, 64);
        AS += __shfl_xor(AS, o, 64);
    }
    if (lane == 0) {
        ASa[s] = AS;
        SLa[s] = SL;
    }
}

// ---------------------------------------------------------------------------
// Final dot product: out = sum_s AS[s]*SL[s] / (T*S), f64 accumulate.
// 1024 threads, shuffle-based reduction.
// ---------------------------------------------------------------------------
__global__ __launch_bounds__(1024) void mepg_reduce(
    const float* __restrict__ ASa, const float* __restrict__ SLa,
    float* __restrict__ out)
{
    __shared__ double sh[16];
    double acc = 0.0;
    for (int i = threadIdx.x; i < S_SIMS; i += 1024)
        acc += (double)ASa[i] * (double)SLa[i];
#pragma unroll
    for (int o = 32; o > 0; o >>= 1)
        acc += __shfl_xor(acc, o, 64);
    const int w = threadIdx.x >> 6, l = threadIdx.x & 63;
    if (l == 0) sh[w] = acc;
    __syncthreads();
    if (threadIdx.x < 16) {
        double a = sh[threadIdx.x];
#pragma unroll
        for (int o = 8; o > 0; o >>= 1)
            a += __shfl_xor(a, o, 16);
        if (threadIdx.x == 0)
            out[0] = (float)(a / ((double)T_LEN * (double)S_SIMS));
    }
}

extern "C" void kernel_launch(void* const* d_in, const int* in_sizes, int n_in,
                              void* d_out, int out_size, void* d_ws, size_t ws_size,
                              hipStream_t stream) {
    const float* state  = (const float*)d_in[0];
    const float* action = (const float*)d_in[1];
    const float* reward = (const float*)d_in[2];
    const float* pW1    = (const float*)d_in[3];
    const float* pb1    = (const float*)d_in[4];
    const float* pW2    = (const float*)d_in[5];
    const float* pb2    = (const float*)d_in[6];
    const float* bW1    = (const float*)d_in[7];
    const float* bb1    = (const float*)d_in[8];
    const float* bW2    = (const float*)d_in[9];
    const float* bb2    = (const float*)d_in[10];
    const float* sd     = (const float*)d_in[11];

    float* ASa = (float*)d_ws;
    float* SLa = ASa + S_SIMS;

    dim3 block(256);
    dim3 grid(S_SIMS / 4);
    mepg_main<<<grid, block, 0, stream>>>(state, action, reward,
                                          pW1, pb1, pW2, pb2,
                                          bW1, bb1, bW2, bb2, sd,
                                          ASa, SLa);
    mepg_reduce<<<1, 1024, 0, stream>>>(ASa, SLa, (float*)d_out);
}